// Round 1
// baseline (159.232 us; speedup 1.0000x reference)
//
#include <hip/hip_runtime.h>

#define IMG_H 256
#define IMG_W 256
#define BAND  32
#define NBANDS (IMG_H / BAND)          // 8
#define NIMG  (128 * 3)                // 384
#define STEPS 64

// bin = clip(ceil((v - 0.02)/RES), 0, 63) computed exactly as the reference (f32 div)
__device__ __forceinline__ int bin_of(float v) {
    const float T_MIN = 0.02f;
    const float RES_F = (float)(0.96 / 63.0);   // (T_MAX-T_MIN)/(STEPS-1)
    int t = (int)ceilf((v - T_MIN) / RES_F);
    t = t < 0 ? 0 : t;
    return t > 63 ? 63 : t;
}

// Each block: one 32-row band of one (b,c) image. Thread j owns column j.
// Max-vertex attribution: every cell (vertex/edge/square) is attributed to its
// lexicographically-largest (value, index) corner; all cells attributed to a
// pixel share its filtration value -> one integer histogram add per pixel.
__global__ __launch_bounds__(256) void ecc_main(const float* __restrict__ x,
                                                int* __restrict__ hist) {
    const int img  = blockIdx.x / NBANDS;
    const int band = blockIdx.x % NBANDS;
    const int j    = threadIdx.x;          // column
    const int wave = j >> 6;

    __shared__ float rows[BAND + 2][IMG_W + 2];  // +inf halo on all sides
    __shared__ int   lh[4][STEPS];               // per-wave histograms

    ((int*)lh)[threadIdx.x] = 0;                 // 4*64 == 256 ints

    const float* base = x + (size_t)img * (IMG_H * IMG_W);
    const int r0 = band * BAND - 1;              // first halo row
#pragma unroll
    for (int k = 0; k < BAND + 2; ++k) {
        int r = r0 + k;
        float v = (r >= 0 && r < IMG_H) ? base[r * IMG_W + j] : 1e30f;
        rows[k][j + 1] = v;
    }
    if (j < BAND + 2) { rows[j][0] = 1e30f; rows[j][IMG_W + 1] = 1e30f; }
    __syncthreads();

    // rolling 3x3 window registers
    float ul = rows[0][j], u = rows[0][j + 1], ur = rows[0][j + 2];
    float l  = rows[1][j], c = rows[1][j + 1], r  = rows[1][j + 2];

    for (int k = 0; k < BAND; ++k) {
        float dl = rows[k + 2][j], d = rows[k + 2][j + 1], dr = rows[k + 2][j + 2];
        if (c <= 0.98f) {                        // reference T_MAX mask
            // neighbor beats p: larger linear idx -> (vq >= vp); smaller -> (vq > vp)
            bool oR = (r  < c);                  // p owns right edge
            bool oL = (l <= c);                  // p owns left edge
            bool oD = (d  < c);
            bool oU = (u <= c);
            bool sDR = oR & oD & (dr <  c);      // square down-right
            bool sDL = oL & oD & (dl <  c);
            bool sUR = oU & oR & (ur <= c);
            bool sUL = oU & oL & (ul <= c);
            int contrib = 1 - ((int)oR + (int)oL + (int)oD + (int)oU)
                            + ((int)sDR + (int)sDL + (int)sUR + (int)sUL);
            if (contrib != 0) atomicAdd(&lh[wave][bin_of(c)], contrib);
        }
        ul = l; u = c; ur = r;
        l = dl; c = d; r = dr;
    }
    __syncthreads();

    if (threadIdx.x < STEPS) {
        int t = threadIdx.x;
        int tot = lh[0][t] + lh[1][t] + lh[2][t] + lh[3][t];
        if (tot) atomicAdd(&hist[img * STEPS + t], tot);
    }
}

// One wave64 per image: inclusive scan over the 64 bins, write float out.
__global__ __launch_bounds__(64) void ecc_scan(const int* __restrict__ hist,
                                               float* __restrict__ out) {
    const int img = blockIdx.x;
    const int t   = threadIdx.x;     // 0..63
    int v = hist[img * STEPS + t];
#pragma unroll
    for (int d = 1; d < 64; d <<= 1) {
        int y = __shfl_up(v, d, 64);
        if (t >= d) v += y;
    }
    out[img * STEPS + t] = (float)v;
}

extern "C" void kernel_launch(void* const* d_in, const int* in_sizes, int n_in,
                              void* d_out, int out_size, void* d_ws, size_t ws_size,
                              hipStream_t stream) {
    const float* x = (const float*)d_in[0];
    float* out = (float*)d_out;
    int* hist = (int*)d_ws;                      // NIMG*STEPS ints (96 KiB)

    hipMemsetAsync(hist, 0, (size_t)NIMG * STEPS * sizeof(int), stream);
    ecc_main<<<dim3(NIMG * NBANDS), dim3(256), 0, stream>>>(x, hist);
    ecc_scan<<<dim3(NIMG), dim3(64), 0, stream>>>(hist, out);
}

// Round 2
// 158.329 us; speedup vs baseline: 1.0057x; 1.0057x over previous
//
#include <hip/hip_runtime.h>

#define IMG     256
#define NIMG    384            // B*C = 128*3
#define STEPS   64
#define ROWS_PT 16             // rows per thread
#define STRIPS  4              // 4 row-strips per block (one per wave)
#define ROWS_PB (ROWS_PT * STRIPS)   // 64 rows per block
#define BANDS   (IMG / ROWS_PB)      // 4 blocks per image
#define INFV    1e30f

// bin = clip(ceil((v - 0.02)/RES), 0, 63) — identical f32 expression to reference
__device__ __forceinline__ int bin_of(float v) {
    const float T_MIN = 0.02f;
    const float RES_F = (float)(0.96 / 63.0);
    int t = (int)ceilf((v - T_MIN) / RES_F);
    t = t < 0 ? 0 : t;
    return t > 63 ? 63 : t;
}

// Load 6-wide window (cols col0-1 .. col0+4) of row r; +inf outside the image.
__device__ __forceinline__ void load_row(const float* __restrict__ base,
                                         int r, int col0, float w[6]) {
    if ((unsigned)r >= IMG) {
        w[0] = w[1] = w[2] = w[3] = w[4] = w[5] = INFV;
        return;
    }
    const float* p = base + r * IMG + col0;
    float4 q = *(const float4*)p;          // col0 % 4 == 0 -> aligned
    w[1] = q.x; w[2] = q.y; w[3] = q.z; w[4] = q.w;
    w[0] = (col0 > 0)       ? p[-1] : INFV;   // L1 hit (neighbor lane's line)
    w[5] = (col0 + 4 < IMG) ? p[4]  : INFV;
}

// Max-vertex attribution: every cell (vertex/edge/square) is attributed to its
// (value, index)-max corner; all cells owned by a pixel share its filtration
// -> single integer LDS-histogram add per pixel. No LDS staging: rolling
// 3-row register window, 3 VMEM ops per 4-pixel group.
__global__ __launch_bounds__(256) void ecc_main(const float* __restrict__ x,
                                                int* __restrict__ hist) {
    const int img   = blockIdx.x / BANDS;
    const int band  = blockIdx.x % BANDS;
    const int lane  = threadIdx.x & 63;
    const int strip = threadIdx.x >> 6;    // == wave id
    const int col0  = lane * 4;
    const int r0    = band * ROWS_PB + strip * ROWS_PT;

    __shared__ int lh[STRIPS][STEPS];      // per-wave sub-histograms
    ((int*)lh)[threadIdx.x] = 0;           // 4*64 == 256
    __syncthreads();

    const float* base = x + (size_t)img * (IMG * IMG);

    float u[6], c[6], d[6];
    load_row(base, r0 - 1, col0, u);
    load_row(base, r0,     col0, c);

    for (int k = 0; k < ROWS_PT; ++k) {
        load_row(base, r0 + k + 1, col0, d);
#pragma unroll
        for (int i = 1; i <= 4; ++i) {
            float cv = c[i];
            if (cv <= 0.98f) {             // reference T_MAX mask
                // neighbor with larger linear idx beats p iff vq >= vp;
                // smaller idx beats p iff vq > vp.
                bool oR = (c[i + 1] <  cv);
                bool oL = (c[i - 1] <= cv);
                bool oD = (d[i]     <  cv);
                bool oU = (u[i]     <= cv);
                bool sDR = oR & oD & (d[i + 1] <  cv);
                bool sDL = oL & oD & (d[i - 1] <  cv);
                bool sUR = oU & oR & (u[i + 1] <= cv);
                bool sUL = oU & oL & (u[i - 1] <= cv);
                int contrib = 1 - ((int)oR + (int)oL + (int)oD + (int)oU)
                                + ((int)sDR + (int)sDL + (int)sUR + (int)sUL);
                if (contrib) atomicAdd(&lh[strip][bin_of(cv)], contrib);
            }
        }
#pragma unroll
        for (int i = 0; i < 6; ++i) { u[i] = c[i]; c[i] = d[i]; }
    }

    __syncthreads();
    if (threadIdx.x < STEPS) {
        int t = threadIdx.x;
        int tot = lh[0][t] + lh[1][t] + lh[2][t] + lh[3][t];
        if (tot) atomicAdd(&hist[img * STEPS + t], tot);
    }
}

// One wave64 per image: inclusive scan over the 64 bins, write float out.
__global__ __launch_bounds__(64) void ecc_scan(const int* __restrict__ hist,
                                               float* __restrict__ out) {
    const int img = blockIdx.x;
    const int t   = threadIdx.x;
    int v = hist[img * STEPS + t];
#pragma unroll
    for (int s = 1; s < 64; s <<= 1) {
        int y = __shfl_up(v, s, 64);
        if (t >= s) v += y;
    }
    out[img * STEPS + t] = (float)v;
}

extern "C" void kernel_launch(void* const* d_in, const int* in_sizes, int n_in,
                              void* d_out, int out_size, void* d_ws, size_t ws_size,
                              hipStream_t stream) {
    const float* x = (const float*)d_in[0];
    float* out = (float*)d_out;
    int* hist = (int*)d_ws;                // NIMG*STEPS ints (96 KiB)

    hipMemsetAsync(hist, 0, (size_t)NIMG * STEPS * sizeof(int), stream);
    ecc_main<<<dim3(NIMG * BANDS), dim3(256), 0, stream>>>(x, hist);
    ecc_scan<<<dim3(NIMG), dim3(64), 0, stream>>>(hist, out);
}